// Round 11
// baseline (198.724 us; speedup 1.0000x reference)
//
#include <hip/hip_runtime.h>
#include <hip/hip_bf16.h>

// ---------- types / helpers ----------
typedef __attribute__((ext_vector_type(8))) short bf16x8;   // 8 bf16 = 4 VGPRs
typedef __attribute__((ext_vector_type(4))) short bf16x4;
typedef __attribute__((ext_vector_type(4))) float f32x4;

__device__ __forceinline__ short f2bf(float f) {
    unsigned u = __float_as_uint(f);
    u += 0x7fff + ((u >> 16) & 1);          // round-to-nearest-even
    return (short)(u >> 16);
}
__device__ __forceinline__ float bf2f(short s) {
    return __uint_as_float(((unsigned)(unsigned short)s) << 16);
}
__device__ __forceinline__ unsigned pk_bf16(float lo, float hi) {
    __hip_bfloat162 t = __float22bfloat162_rn(make_float2(lo, hi));
    unsigned u;
    __builtin_memcpy(&u, &t, 4);
    return u;
}

#define GLOAD_LDS16(gp, lp)                                                            \
    __builtin_amdgcn_global_load_lds(                                                  \
        (const __attribute__((address_space(1))) unsigned*)(gp),                       \
        (__attribute__((address_space(3))) unsigned*)(lp), 16, 0, 0)

#define QK_SCALE 0.180336879f   // (1/sqrt(64)) * log2(e), folded into q at GEMM1
#define MFMA16(a, b, c) __builtin_amdgcn_mfma_f32_16x16x32_bf16((a), (b), (c), 0, 0, 0)

// ---------- fused prep: enc->bf16, biases->bf16, Wa/Wo -> transposed bf16 ----------
__device__ __forceinline__ void tcvt_tile(const float* __restrict__ W, short* __restrict__ Wt,
                                          int K, int N, int bx, int by, int t,
                                          short (*tile)[72]) {
    const int k0 = by * 64, n0 = bx * 64;
    #pragma unroll
    for (int jj = 0; jj < 4; ++jj) {
        int row = jj * 16 + (t >> 4);
        int col = (t & 15) * 4;
        f32x4 v = *(const f32x4*)&W[(size_t)(k0 + row) * N + n0 + col];
        bf16x4 b = {f2bf(v.x), f2bf(v.y), f2bf(v.z), f2bf(v.w)};
        *(bf16x4*)&tile[row][col] = b;
    }
    __syncthreads();
    const int nr = t >> 2, kc = (t & 3) * 16;
    bf16x8 o0, o1;
    #pragma unroll
    for (int j = 0; j < 8; ++j) { o0[j] = tile[kc + j][nr]; o1[j] = tile[kc + 8 + j][nr]; }
    short* dst = &Wt[(size_t)(n0 + nr) * K + k0 + kc];
    *(bf16x8*)dst = o0;
    *(bf16x8*)(dst + 8) = o1;
}

__global__ __launch_bounds__(256) void prep_kernel(
    const float* __restrict__ enc, const float* __restrict__ Wa,
    const float* __restrict__ ba, const float* __restrict__ Wo,
    const float* __restrict__ bo, short* __restrict__ Abf,
    short* __restrict__ WtA, short* __restrict__ bbA,
    short* __restrict__ WtO, short* __restrict__ bbO)
{
    __shared__ alignas(16) short tile[64][72];
    const int id = blockIdx.x, t = threadIdx.x;
    if (id < 2048) {
        const int i = id * 2048 + t * 8;
        f32x4 a = *(const f32x4*)&enc[i];
        f32x4 b = *(const f32x4*)&enc[i + 4];
        bf16x8 o = {f2bf(a.x), f2bf(a.y), f2bf(a.z), f2bf(a.w),
                    f2bf(b.x), f2bf(b.y), f2bf(b.z), f2bf(b.w)};
        *(bf16x8*)&Abf[i] = o;
    } else if (id == 2048) {
        for (int j = t * 8; j < 3072; j += 2048) {
            f32x4 a = *(const f32x4*)&ba[j];
            f32x4 b = *(const f32x4*)&ba[j + 4];
            bf16x8 o = {f2bf(a.x), f2bf(a.y), f2bf(a.z), f2bf(a.w),
                        f2bf(b.x), f2bf(b.y), f2bf(b.z), f2bf(b.w)};
            *(bf16x8*)&bbA[j] = o;
        }
    } else if (id == 2049) {
        if (t < 128) {
            const int j = t * 8;
            f32x4 a = *(const f32x4*)&bo[j];
            f32x4 b = *(const f32x4*)&bo[j + 4];
            bf16x8 o = {f2bf(a.x), f2bf(a.y), f2bf(a.z), f2bf(a.w),
                        f2bf(b.x), f2bf(b.y), f2bf(b.z), f2bf(b.w)};
            *(bf16x8*)&bbO[j] = o;
        }
        __syncthreads();
    } else if (id < 2818) {
        const int lid = id - 2050;
        tcvt_tile(Wa, WtA, 1024, 3072, lid % 48, lid / 48, t, tile);
    } else {
        const int lid = id - 2818;
        tcvt_tile(Wo, WtO, 1024, 1024, lid % 16, lid / 16, t, tile);
    }
}

// ---------- m97-style BT GEMM: C = A @ Bt^T + bias ----------
// SPLIT3: N=3072, col group g=n0>>10 routes: g0 -> Qw row-major (scaled),
// g1 -> Kx fragment order, g2 -> Vx fragment order (fused fragprep).
// Kx[bh][kc][(s*2+h)*64+lane][j] = K[kc*64+s*16+(lane&15)][h*32+(lane>>4)*8+j]
// Vx[bh][kc][(h*4+dt)*64+lane][j] = V[kc*64+h*32+(lane>>4)*8+j][dt*16+(lane&15)]
template<int BN, bool F32OUT, bool SPLIT3>
__global__ __launch_bounds__(256) void gemm_bt(
    const short* __restrict__ A, const short* __restrict__ Bt,
    const short* __restrict__ bias, void* __restrict__ C,
    short* __restrict__ Kx, short* __restrict__ Vx, int M, int N, int K)
{
    __shared__ alignas(16) short As[128 * 32];
    __shared__ alignas(16) short Bs[BN * 32];

    const int tid = threadIdx.x, w = tid >> 6, lane = tid & 63;
    const int quad = lane >> 4, l16 = lane & 15;
    constexpr int MT = (BN == 128) ? 4 : 2;
    const int wm = (BN == 128) ? (w >> 1) : w;
    const int wn = (BN == 128) ? (w & 1) : 0;
    const int m0 = blockIdx.y * 128, n0 = blockIdx.x * BN;
    const int srow = lane >> 2, scol = (lane & 3) * 8;

    f32x4 acc[MT][4] = {};

    for (int k0 = 0; k0 < K; k0 += 32) {
        __syncthreads();
        #pragma unroll
        for (int jj = 0; jj < 2; ++jj) {
            const int rb = w * 32 + jj * 16;
            GLOAD_LDS16(&A[(size_t)(m0 + rb + srow) * K + k0 + scol], &As[rb * 32]);
        }
        if (BN == 128) {
            #pragma unroll
            for (int jj = 0; jj < 2; ++jj) {
                const int rb = w * 32 + jj * 16;
                GLOAD_LDS16(&Bt[(size_t)(n0 + rb + srow) * K + k0 + scol], &Bs[rb * 32]);
            }
        } else {
            const int rb = w * 16;
            GLOAD_LDS16(&Bt[(size_t)(n0 + rb + srow) * K + k0 + scol], &Bs[rb * 32]);
        }
        __syncthreads();
        bf16x8 af[MT], bfr[4];
        #pragma unroll
        for (int i = 0; i < MT; ++i)
            af[i] = *(const bf16x8*)&As[(wm * (MT * 16) + i * 16 + l16) * 32 + quad * 8];
        #pragma unroll
        for (int i = 0; i < 4; ++i)
            bfr[i] = *(const bf16x8*)&Bs[(wn * 64 + i * 16 + l16) * 32 + quad * 8];
        #pragma unroll
        for (int mt = 0; mt < MT; ++mt)
            #pragma unroll
            for (int nt = 0; nt < 4; ++nt)
                acc[mt][nt] = MFMA16(af[mt], bfr[nt], acc[mt][nt]);
    }

    if (SPLIT3) {
        const int g = n0 >> 10;                     // 0=q,1=k,2=v (block-uniform)
        if (g == 0) {
            short* qw = (short*)C;
            #pragma unroll
            for (int nt = 0; nt < 4; ++nt) {
                const int col = n0 + wn * 64 + nt * 16 + l16;
                const int lc = col & 1023;
                const float bv = bf2f(bias[col]);
                #pragma unroll
                for (int mt = 0; mt < 4; ++mt) {
                    const int row = m0 + wm * 64 + mt * 16 + quad * 4;
                    #pragma unroll
                    for (int r = 0; r < 4; ++r)
                        qw[(size_t)(row + r) * 1024 + lc] = f2bf((acc[mt][nt][r] + bv) * QK_SCALE);
                }
            }
        } else if (g == 1) {
            // K -> Kx fragment order (scalar scatter, same cost as row-major)
            #pragma unroll
            for (int nt = 0; nt < 4; ++nt) {
                const int col = n0 + wn * 64 + nt * 16 + l16;
                const int lc = col & 1023, head = lc >> 6, d = lc & 63;
                const int h = d >> 5, qk = (d & 31) >> 3, j = d & 7;
                const float bv = bf2f(bias[col]);
                #pragma unroll
                for (int mt = 0; mt < 4; ++mt) {
                    const int rowA = m0 + wm * 64 + mt * 16 + quad * 4;
                    const int batch = rowA >> 11, seq = rowA & 2047, kc = seq >> 6;
                    const int bh = batch * 16 + head;
                    short* base = &Kx[((size_t)bh * 32 + kc) * 4096
                                      + ((mt * 2 + h) * 64 + qk * 16 + quad * 4) * 8 + j];
                    #pragma unroll
                    for (int r = 0; r < 4; ++r)
                        base[r * 8] = f2bf(acc[mt][nt][r] + bv);
                }
            }
        } else {
            // V -> Vx fragment order: lane's 4 values are contiguous -> bf16x4 store
            #pragma unroll
            for (int nt = 0; nt < 4; ++nt) {
                const int col = n0 + wn * 64 + nt * 16 + l16;
                const int lc = col & 1023, head = lc >> 6, d = lc & 63;
                const int dt = d >> 4, l16v = d & 15;
                const float bv = bf2f(bias[col]);
                #pragma unroll
                for (int mt = 0; mt < 4; ++mt) {
                    const int rowA = m0 + wm * 64 + mt * 16 + quad * 4;
                    const int batch = rowA >> 11, seq = rowA & 2047, kc = seq >> 6;
                    const int s64 = seq & 63;                 // = mt*16 + quad*4
                    const int h = s64 >> 5, q2 = (s64 & 31) >> 3, j0 = s64 & 7;
                    const int bh = batch * 16 + head;
                    bf16x4 pk;
                    #pragma unroll
                    for (int r = 0; r < 4; ++r) pk[r] = f2bf(acc[mt][nt][r] + bv);
                    *(bf16x4*)&Vx[((size_t)bh * 32 + kc) * 4096
                                  + ((h * 4 + dt) * 64 + q2 * 16 + l16v) * 8 + j0] = pk;
                }
            }
        }
    } else {
        #pragma unroll
        for (int nt = 0; nt < 4; ++nt) {
            const int col = n0 + wn * 64 + nt * 16 + l16;
            const float bv = bf2f(bias[col]);
            #pragma unroll
            for (int mt = 0; mt < MT; ++mt) {
                const int row = m0 + wm * (MT * 16) + mt * 16 + quad * 4;
                #pragma unroll
                for (int r = 0; r < 4; ++r) {
                    float v = acc[mt][nt][r] + bv;
                    if (F32OUT) ((float*)C)[(size_t)(row + r) * N + col] = v;
                    else        ((short*)C)[(size_t)(row + r) * N + col] = f2bf(v);
                }
            }
        }
    }
}

// ---------- barrier-free causal flash attention, fragment-coalesced loads ----------
// Paired {tA,63-tA} 32-row tiles, K prefetch, static-max softmax, S^T form.
// K/V read from Kx/Vx in fragment order: each load = contiguous 1KB b128.
__global__ __launch_bounds__(128) void attn_kernel(
    const short* __restrict__ Qw, const short* __restrict__ Kx,
    const short* __restrict__ Vx, short* __restrict__ comb)
{
    __shared__ alignas(16) short Ps[2][2][16 * 72];   // [wave][tile A/B]

    const int tid = threadIdx.x, w = tid >> 6, lane = tid & 63;
    const int quad = lane >> 4, l16 = lane & 15;
    const int bh = blockIdx.x;
    const int tA = blockIdx.y, tB = 63 - tA;
    const int batch = bh >> 4, head = bh & 15;
    const size_t rowbase = (size_t)batch * 2048;
    const int hcol = head * 64;
    const int q0A = tA * 32 + w * 16, q0B = tB * 32 + w * 16;
    const int diagA = tA >> 1, diagB = tB >> 1;
    const short* Kxbh = Kx + (size_t)bh * 131072;
    const short* Vxbh = Vx + (size_t)bh * 131072;
    const int lofs = lane * 8;
    short* pwA = &Ps[w][0][0];
    short* pwB = &Ps[w][1][0];

    // Q fragments (B-operand: q = l16, d = quad*8+j (+32))
    bf16x8 qfA[2], qfB[2];
    {
        const short* pa = &Qw[(rowbase + q0A + l16) * 1024 + hcol];
        const short* pb = &Qw[(rowbase + q0B + l16) * 1024 + hcol];
        qfA[0] = *(const bf16x8*)(pa + quad * 8);
        qfA[1] = *(const bf16x8*)(pa + 32 + quad * 8);
        qfB[0] = *(const bf16x8*)(pb + quad * 8);
        qfB[1] = *(const bf16x8*)(pb + 32 + quad * 8);
    }

    f32x4 otA[4] = {}, otB[4] = {};
    float laccA = 0.f, laccB = 0.f;

    // preload K fragments for step 0 (coalesced chunks)
    bf16x8 kf[4][2];
    #pragma unroll
    for (int s = 0; s < 4; ++s) {
        kf[s][0] = *(const bf16x8*)&Kxbh[(s * 2 + 0) * 512 + lofs];
        kf[s][1] = *(const bf16x8*)&Kxbh[(s * 2 + 1) * 512 + lofs];
    }

    for (int kc = 0; kc <= diagB; ++kc) {
        const bool actA = (kc <= diagA);
        const int key0 = kc * 64;

        // V fragments for current step — issued early, consumed at step end
        const short* vb = Vxbh + kc * 4096;
        bf16x8 vf[2][4];
        #pragma unroll
        for (int h = 0; h < 2; ++h)
            #pragma unroll
            for (int dt = 0; dt < 4; ++dt)
                vf[h][dt] = *(const bf16x8*)&vb[(h * 4 + dt) * 512 + lofs];

        // ---- QK (S^T = K.Q^T): consumes kf ----
        f32x4 svA[4], svB[4];
        #pragma unroll
        for (int s = 0; s < 4; ++s) {
            f32x4 a = {0.f, 0.f, 0.f, 0.f};
            a = MFMA16(kf[s][0], qfB[0], a);
            a = MFMA16(kf[s][1], qfB[1], a);
            svB[s] = a;
            if (actA) {
                f32x4 b = {0.f, 0.f, 0.f, 0.f};
                b = MFMA16(kf[s][0], qfA[0], b);
                b = MFMA16(kf[s][1], qfA[1], b);
                svA[s] = b;
            }
        }

        // ---- prefetch next step's K (off critical path) ----
        if (kc < diagB) {
            const short* kb = Kxbh + (kc + 1) * 4096;
            #pragma unroll
            for (int s = 0; s < 4; ++s) {
                kf[s][0] = *(const bf16x8*)&kb[(s * 2 + 0) * 512 + lofs];
                kf[s][1] = *(const bf16x8*)&kb[(s * 2 + 1) * 512 + lofs];
            }
        }

        // ---- softmax + P^T -> per-wave LDS (8B packed writes) ----
        if (kc == diagB) {
            const int qq = q0B + l16;
            #pragma unroll
            for (int s = 0; s < 4; ++s) {
                const int keyb = key0 + s * 16 + quad * 4;
                #pragma unroll
                for (int r = 0; r < 4; ++r)
                    svB[s][r] = (keyb + r <= qq) ? svB[s][r] : -1e30f;
            }
        }
        #pragma unroll
        for (int s = 0; s < 4; ++s) {
            #pragma unroll
            for (int r = 0; r < 4; ++r) svB[s][r] = exp2f(svB[s][r]);
            laccB += (svB[s][0] + svB[s][1]) + (svB[s][2] + svB[s][3]);
            uint2 pk = {pk_bf16(svB[s][0], svB[s][1]), pk_bf16(svB[s][2], svB[s][3])};
            *(uint2*)&pwB[l16 * 72 + s * 16 + quad * 4] = pk;
        }
        if (actA) {
            if (kc == diagA) {
                const int qq = q0A + l16;
                #pragma unroll
                for (int s = 0; s < 4; ++s) {
                    const int keyb = key0 + s * 16 + quad * 4;
                    #pragma unroll
                    for (int r = 0; r < 4; ++r)
                        svA[s][r] = (keyb + r <= qq) ? svA[s][r] : -1e30f;
                }
            }
            #pragma unroll
            for (int s = 0; s < 4; ++s) {
                #pragma unroll
                for (int r = 0; r < 4; ++r) svA[s][r] = exp2f(svA[s][r]);
                laccA += (svA[s][0] + svA[s][1]) + (svA[s][2] + svA[s][3]);
                uint2 pk = {pk_bf16(svA[s][0], svA[s][1]), pk_bf16(svA[s][2], svA[s][3])};
                *(uint2*)&pwA[l16 * 72 + s * 16 + quad * 4] = pk;
            }
        }

        // ---- PV (O^T += V^T.P^T); wave-internal DS is in-order ----
        {
            bf16x8 pfB0 = *(const bf16x8*)&pwB[l16 * 72 + quad * 8];
            bf16x8 pfB1 = *(const bf16x8*)&pwB[l16 * 72 + 32 + quad * 8];
            #pragma unroll
            for (int dt = 0; dt < 4; ++dt) {
                otB[dt] = MFMA16(vf[0][dt], pfB0, otB[dt]);
                otB[dt] = MFMA16(vf[1][dt], pfB1, otB[dt]);
            }
            if (actA) {
                bf16x8 pfA0 = *(const bf16x8*)&pwA[l16 * 72 + quad * 8];
                bf16x8 pfA1 = *(const bf16x8*)&pwA[l16 * 72 + 32 + quad * 8];
                #pragma unroll
                for (int dt = 0; dt < 4; ++dt) {
                    otA[dt] = MFMA16(vf[0][dt], pfA0, otA[dt]);
                    otA[dt] = MFMA16(vf[1][dt], pfA1, otA[dt]);
                }
            }
        }
    }

    // ---- l reduction (lanes sharing l16 across quads) + epilogue ----
    laccA += __shfl_xor(laccA, 16);
    laccA += __shfl_xor(laccA, 32);
    laccB += __shfl_xor(laccB, 16);
    laccB += __shfl_xor(laccB, 32);
    const float invA = 1.0f / laccA, invB = 1.0f / laccB;

    #pragma unroll
    for (int dt = 0; dt < 4; ++dt) {
        uint2 pa = {pk_bf16(otA[dt][0] * invA, otA[dt][1] * invA),
                    pk_bf16(otA[dt][2] * invA, otA[dt][3] * invA)};
        *(uint2*)&pwA[l16 * 72 + dt * 16 + quad * 4] = pa;
        uint2 pb = {pk_bf16(otB[dt][0] * invB, otB[dt][1] * invB),
                    pk_bf16(otB[dt][2] * invB, otB[dt][3] * invB)};
        *(uint2*)&pwB[l16 * 72 + dt * 16 + quad * 4] = pb;
    }
    {
        const int qr = lane >> 2, dc = (lane & 3) * 16;
        bf16x8 a0 = *(const bf16x8*)&pwA[qr * 72 + dc];
        bf16x8 a1 = *(const bf16x8*)&pwA[qr * 72 + dc + 8];
        short* dstA = &comb[(rowbase + q0A + qr) * 1024 + hcol + dc];
        *(bf16x8*)dstA = a0;
        *(bf16x8*)(dstA + 8) = a1;
        bf16x8 b0 = *(const bf16x8*)&pwB[qr * 72 + dc];
        bf16x8 b1 = *(const bf16x8*)&pwB[qr * 72 + dc + 8];
        short* dstB = &comb[(rowbase + q0B + qr) * 1024 + hcol + dc];
        *(bf16x8*)dstB = b0;
        *(bf16x8*)(dstB + 8) = b1;
    }
}

// ---------- launch ----------
extern "C" void kernel_launch(void* const* d_in, const int* in_sizes, int n_in,
                              void* d_out, int out_size, void* d_ws, size_t ws_size,
                              hipStream_t stream)
{
    const float* enc = (const float*)d_in[0];
    const float* Wa  = (const float*)d_in[1];
    const float* ba  = (const float*)d_in[2];
    const float* Wo  = (const float*)d_in[3];
    const float* bo  = (const float*)d_in[4];
    float* out = (float*)d_out;

    // layout (41 MB peak):
    // [0,8)  Abf (dead after gemm1) -> comb
    // [8,10) WtO  [10,11) biases  [11,17) WtA
    // [17,25) Kx  [25,33) Vx  [33,41) Qw
    char* ws = (char*)d_ws;
    short* Abf  = (short*)ws;
    short* comb = (short*)ws;
    short* WtO  = (short*)(ws + ((size_t)8 << 20));
    short* bbA  = (short*)(ws + ((size_t)10 << 20));
    short* bbO  = (short*)(ws + ((size_t)10 << 20) + 16384);
    short* WtA  = (short*)(ws + ((size_t)11 << 20));
    short* Kx   = (short*)(ws + ((size_t)17 << 20));
    short* Vx   = (short*)(ws + ((size_t)25 << 20));
    short* Qw   = (short*)(ws + ((size_t)33 << 20));

    prep_kernel<<<3074, 256, 0, stream>>>(enc, Wa, ba, Wo, bo, Abf, WtA, bbA, WtO, bbO);
    gemm_bt<128, false, true><<<dim3(24, 32), 256, 0, stream>>>(
        Abf, WtA, bbA, Qw, Kx, Vx, 4096, 3072, 1024);
    attn_kernel<<<dim3(32, 32), 128, 0, stream>>>(Qw, Kx, Vx, comb);
    gemm_bt<64, true, false><<<dim3(16, 32), 256, 0, stream>>>(
        comb, WtO, bbO, out, nullptr, nullptr, 4096, 1024, 1024);
}

// Round 12
// 196.653 us; speedup vs baseline: 1.0105x; 1.0105x over previous
//
#include <hip/hip_runtime.h>
#include <hip/hip_bf16.h>

// ---------- types / helpers ----------
typedef __attribute__((ext_vector_type(8))) short bf16x8;   // 8 bf16 = 4 VGPRs
typedef __attribute__((ext_vector_type(4))) short bf16x4;
typedef __attribute__((ext_vector_type(4))) float f32x4;

__device__ __forceinline__ short f2bf(float f) {
    unsigned u = __float_as_uint(f);
    u += 0x7fff + ((u >> 16) & 1);          // round-to-nearest-even
    return (short)(u >> 16);
}
__device__ __forceinline__ float bf2f(short s) {
    return __uint_as_float(((unsigned)(unsigned short)s) << 16);
}
__device__ __forceinline__ unsigned pk_bf16(float lo, float hi) {
    __hip_bfloat162 t = __float22bfloat162_rn(make_float2(lo, hi));
    unsigned u;
    __builtin_memcpy(&u, &t, 4);
    return u;
}

#define GLOAD_LDS16(gp, lp)                                                            \
    __builtin_amdgcn_global_load_lds(                                                  \
        (const __attribute__((address_space(1))) unsigned*)(gp),                       \
        (__attribute__((address_space(3))) unsigned*)(lp), 16, 0, 0)

#define QK_SCALE 0.180336879f   // (1/sqrt(64)) * log2(e), folded into q at GEMM1
#define MFMA16(a, b, c) __builtin_amdgcn_mfma_f32_16x16x32_bf16((a), (b), (c), 0, 0, 0)

// ---------- fused prep: enc->bf16, biases->bf16, Wa/Wo -> transposed bf16 ----------
__device__ __forceinline__ void tcvt_tile(const float* __restrict__ W, short* __restrict__ Wt,
                                          int K, int N, int bx, int by, int t,
                                          short (*tile)[72]) {
    const int k0 = by * 64, n0 = bx * 64;
    #pragma unroll
    for (int jj = 0; jj < 4; ++jj) {
        int row = jj * 16 + (t >> 4);
        int col = (t & 15) * 4;
        f32x4 v = *(const f32x4*)&W[(size_t)(k0 + row) * N + n0 + col];
        bf16x4 b = {f2bf(v.x), f2bf(v.y), f2bf(v.z), f2bf(v.w)};
        *(bf16x4*)&tile[row][col] = b;
    }
    __syncthreads();
    const int nr = t >> 2, kc = (t & 3) * 16;
    bf16x8 o0, o1;
    #pragma unroll
    for (int j = 0; j < 8; ++j) { o0[j] = tile[kc + j][nr]; o1[j] = tile[kc + 8 + j][nr]; }
    short* dst = &Wt[(size_t)(n0 + nr) * K + k0 + kc];
    *(bf16x8*)dst = o0;
    *(bf16x8*)(dst + 8) = o1;
}

__global__ __launch_bounds__(256) void prep_kernel(
    const float* __restrict__ enc, const float* __restrict__ Wa,
    const float* __restrict__ ba, const float* __restrict__ Wo,
    const float* __restrict__ bo, short* __restrict__ Abf,
    short* __restrict__ WtA, short* __restrict__ bbA,
    short* __restrict__ WtO, short* __restrict__ bbO)
{
    __shared__ alignas(16) short tile[64][72];
    const int id = blockIdx.x, t = threadIdx.x;
    if (id < 2048) {
        const int i = id * 2048 + t * 8;
        f32x4 a = *(const f32x4*)&enc[i];
        f32x4 b = *(const f32x4*)&enc[i + 4];
        bf16x8 o = {f2bf(a.x), f2bf(a.y), f2bf(a.z), f2bf(a.w),
                    f2bf(b.x), f2bf(b.y), f2bf(b.z), f2bf(b.w)};
        *(bf16x8*)&Abf[i] = o;
    } else if (id == 2048) {
        for (int j = t * 8; j < 3072; j += 2048) {
            f32x4 a = *(const f32x4*)&ba[j];
            f32x4 b = *(const f32x4*)&ba[j + 4];
            bf16x8 o = {f2bf(a.x), f2bf(a.y), f2bf(a.z), f2bf(a.w),
                        f2bf(b.x), f2bf(b.y), f2bf(b.z), f2bf(b.w)};
            *(bf16x8*)&bbA[j] = o;
        }
    } else if (id == 2049) {
        if (t < 128) {
            const int j = t * 8;
            f32x4 a = *(const f32x4*)&bo[j];
            f32x4 b = *(const f32x4*)&bo[j + 4];
            bf16x8 o = {f2bf(a.x), f2bf(a.y), f2bf(a.z), f2bf(a.w),
                        f2bf(b.x), f2bf(b.y), f2bf(b.z), f2bf(b.w)};
            *(bf16x8*)&bbO[j] = o;
        }
        __syncthreads();
    } else if (id < 2818) {
        const int lid = id - 2050;
        tcvt_tile(Wa, WtA, 1024, 3072, lid % 48, lid / 48, t, tile);
    } else {
        const int lid = id - 2818;
        tcvt_tile(Wo, WtO, 1024, 1024, lid % 16, lid / 16, t, tile);
    }
}

// ---------- m97-style BT GEMM: C = A @ Bt^T + bias ----------
// SPLIT3: N=3072, col group g=n0>>10: g0 -> Qw row-major (scaled); g1/g2 ->
// Kx/Vx fragment order via LDS-coalesced epilogue (stage 128x128 tile in LDS,
// emit fragment chunks as coalesced b128 stores).
// Kx[bh][kc][(s*2+h)*64+lane][j] = K[kc*64+s*16+(lane&15)][h*32+(lane>>4)*8+j]
// Vx[bh][kc][(h*4+dt)*64+lane][j] = V[kc*64+h*32+(lane>>4)*8+j][dt*16+(lane&15)]
template<int BN, bool F32OUT, bool SPLIT3>
__global__ __launch_bounds__(256) void gemm_bt(
    const short* __restrict__ A, const short* __restrict__ Bt,
    const short* __restrict__ bias, void* __restrict__ C,
    short* __restrict__ Kx, short* __restrict__ Vx, int M, int N, int K)
{
    constexpr int TSTRIDE = 136;   // shorts; 272B rows keep 16B alignment
    constexpr int SMSZ = SPLIT3 ? (128 * TSTRIDE) : (128 * 32 + BN * 32);
    __shared__ alignas(16) short SMEM[SMSZ];
    short* As = SMEM;
    short* Bs = SMEM + 128 * 32;

    const int tid = threadIdx.x, w = tid >> 6, lane = tid & 63;
    const int quad = lane >> 4, l16 = lane & 15;
    constexpr int MT = (BN == 128) ? 4 : 2;
    const int wm = (BN == 128) ? (w >> 1) : w;
    const int wn = (BN == 128) ? (w & 1) : 0;
    const int m0 = blockIdx.y * 128, n0 = blockIdx.x * BN;
    const int srow = lane >> 2, scol = (lane & 3) * 8;

    f32x4 acc[MT][4] = {};

    for (int k0 = 0; k0 < K; k0 += 32) {
        __syncthreads();
        #pragma unroll
        for (int jj = 0; jj < 2; ++jj) {
            const int rb = w * 32 + jj * 16;
            GLOAD_LDS16(&A[(size_t)(m0 + rb + srow) * K + k0 + scol], &As[rb * 32]);
        }
        if (BN == 128) {
            #pragma unroll
            for (int jj = 0; jj < 2; ++jj) {
                const int rb = w * 32 + jj * 16;
                GLOAD_LDS16(&Bt[(size_t)(n0 + rb + srow) * K + k0 + scol], &Bs[rb * 32]);
            }
        } else {
            const int rb = w * 16;
            GLOAD_LDS16(&Bt[(size_t)(n0 + rb + srow) * K + k0 + scol], &Bs[rb * 32]);
        }
        __syncthreads();
        bf16x8 af[MT], bfr[4];
        #pragma unroll
        for (int i = 0; i < MT; ++i)
            af[i] = *(const bf16x8*)&As[(wm * (MT * 16) + i * 16 + l16) * 32 + quad * 8];
        #pragma unroll
        for (int i = 0; i < 4; ++i)
            bfr[i] = *(const bf16x8*)&Bs[(wn * 64 + i * 16 + l16) * 32 + quad * 8];
        #pragma unroll
        for (int mt = 0; mt < MT; ++mt)
            #pragma unroll
            for (int nt = 0; nt < 4; ++nt)
                acc[mt][nt] = MFMA16(af[mt], bfr[nt], acc[mt][nt]);
    }

    if (SPLIT3) {
        const int g = n0 >> 10;                     // 0=q,1=k,2=v (block-uniform)
        if (g == 0) {
            short* qw = (short*)C;
            #pragma unroll
            for (int nt = 0; nt < 4; ++nt) {
                const int col = n0 + wn * 64 + nt * 16 + l16;
                const int lc = col & 1023;
                const float bv = bf2f(bias[col]);
                #pragma unroll
                for (int mt = 0; mt < 4; ++mt) {
                    const int row = m0 + wm * 64 + mt * 16 + quad * 4;
                    #pragma unroll
                    for (int r = 0; r < 4; ++r)
                        qw[(size_t)(row + r) * 1024 + lc] = f2bf((acc[mt][nt][r] + bv) * QK_SCALE);
                }
            }
        } else {
            // stage 128x128 output tile in LDS, then coalesced fragment writes
            short* T = SMEM;
            __syncthreads();     // all waves done reading As/Bs
            if (g == 1) {
                // T[key][d]
                #pragma unroll
                for (int nt = 0; nt < 4; ++nt) {
                    const float bv = bf2f(bias[n0 + wn * 64 + nt * 16 + l16]);
                    #pragma unroll
                    for (int mt = 0; mt < 4; ++mt)
                        #pragma unroll
                        for (int r = 0; r < 4; ++r)
                            T[(wm * 64 + mt * 16 + quad * 4 + r) * TSTRIDE
                              + wn * 64 + nt * 16 + l16] = f2bf(acc[mt][nt][r] + bv);
                }
            } else {
                // T[d][key]
                #pragma unroll
                for (int nt = 0; nt < 4; ++nt) {
                    const float bv = bf2f(bias[n0 + wn * 64 + nt * 16 + l16]);
                    #pragma unroll
                    for (int mt = 0; mt < 4; ++mt)
                        #pragma unroll
                        for (int r = 0; r < 4; ++r)
                            T[(wn * 64 + nt * 16 + l16) * TSTRIDE
                              + wm * 64 + mt * 16 + quad * 4 + r] = f2bf(acc[mt][nt][r] + bv);
                }
            }
            __syncthreads();
            // readout: 4 fragment tiles (2 heads x 2 kc), 64 threads each
            const int batch = m0 >> 11, kc0 = (m0 & 2047) >> 6;
            const int head0 = (n0 & 1023) >> 6;
            const int tsel = tid >> 6, lane2 = tid & 63;
            const int th = tsel & 1, tk = tsel >> 1;
            const int bh = batch * 16 + head0 + th;
            short* dst = (g == 1 ? Kx : Vx) + ((size_t)bh * 32 + kc0 + tk) * 4096;
            #pragma unroll
            for (int i = 0; i < 8; ++i) {
                int row, col;
                if (g == 1) {  // chunk c=(s*2+h)*64+lane2: s=i>>1, h=i&1
                    row = tk * 64 + (i >> 1) * 16 + (lane2 & 15);
                    col = th * 64 + (i & 1) * 32 + (lane2 >> 4) * 8;
                } else {       // chunk c=(h*4+dt)*64+lane2: h=i>>2, dt=i&3
                    row = th * 64 + (i & 3) * 16 + (lane2 & 15);
                    col = tk * 64 + (i >> 2) * 32 + (lane2 >> 4) * 8;
                }
                bf16x8 v = *(const bf16x8*)&T[row * TSTRIDE + col];
                *(bf16x8*)&dst[(i * 64 + lane2) * 8] = v;
            }
        }
    } else {
        #pragma unroll
        for (int nt = 0; nt < 4; ++nt) {
            const int col = n0 + wn * 64 + nt * 16 + l16;
            const float bv = bf2f(bias[col]);
            #pragma unroll
            for (int mt = 0; mt < MT; ++mt) {
                const int row = m0 + wm * (MT * 16) + mt * 16 + quad * 4;
                #pragma unroll
                for (int r = 0; r < 4; ++r) {
                    float v = acc[mt][nt][r] + bv;
                    if (F32OUT) ((float*)C)[(size_t)(row + r) * N + col] = v;
                    else        ((short*)C)[(size_t)(row + r) * N + col] = f2bf(v);
                }
            }
        }
    }
}

// ---------- barrier-free causal flash attention, fragment-coalesced loads ----------
// Paired {tA,63-tA} 32-row tiles, K prefetch, static-max softmax, S^T form.
// K/V read from Kx/Vx in fragment order: each load = contiguous 1KB b128.
__global__ __launch_bounds__(128) void attn_kernel(
    const short* __restrict__ Qw, const short* __restrict__ Kx,
    const short* __restrict__ Vx, short* __restrict__ comb)
{
    __shared__ alignas(16) short Ps[2][2][16 * 72];   // [wave][tile A/B]

    const int tid = threadIdx.x, w = tid >> 6, lane = tid & 63;
    const int quad = lane >> 4, l16 = lane & 15;
    const int bh = blockIdx.x;
    const int tA = blockIdx.y, tB = 63 - tA;
    const int batch = bh >> 4, head = bh & 15;
    const size_t rowbase = (size_t)batch * 2048;
    const int hcol = head * 64;
    const int q0A = tA * 32 + w * 16, q0B = tB * 32 + w * 16;
    const int diagA = tA >> 1, diagB = tB >> 1;
    const short* Kxbh = Kx + (size_t)bh * 131072;
    const short* Vxbh = Vx + (size_t)bh * 131072;
    const int lofs = lane * 8;
    short* pwA = &Ps[w][0][0];
    short* pwB = &Ps[w][1][0];

    // Q fragments (B-operand: q = l16, d = quad*8+j (+32))
    bf16x8 qfA[2], qfB[2];
    {
        const short* pa = &Qw[(rowbase + q0A + l16) * 1024 + hcol];
        const short* pb = &Qw[(rowbase + q0B + l16) * 1024 + hcol];
        qfA[0] = *(const bf16x8*)(pa + quad * 8);
        qfA[1] = *(const bf16x8*)(pa + 32 + quad * 8);
        qfB[0] = *(const bf16x8*)(pb + quad * 8);
        qfB[1] = *(const bf16x8*)(pb + 32 + quad * 8);
    }

    f32x4 otA[4] = {}, otB[4] = {};
    float laccA = 0.f, laccB = 0.f;

    // preload K fragments for step 0 (coalesced chunks)
    bf16x8 kf[4][2];
    #pragma unroll
    for (int s = 0; s < 4; ++s) {
        kf[s][0] = *(const bf16x8*)&Kxbh[(s * 2 + 0) * 512 + lofs];
        kf[s][1] = *(const bf16x8*)&Kxbh[(s * 2 + 1) * 512 + lofs];
    }

    for (int kc = 0; kc <= diagB; ++kc) {
        const bool actA = (kc <= diagA);
        const int key0 = kc * 64;

        // V fragments for current step — issued early, consumed at step end
        const short* vb = Vxbh + kc * 4096;
        bf16x8 vf[2][4];
        #pragma unroll
        for (int h = 0; h < 2; ++h)
            #pragma unroll
            for (int dt = 0; dt < 4; ++dt)
                vf[h][dt] = *(const bf16x8*)&vb[(h * 4 + dt) * 512 + lofs];

        // ---- QK (S^T = K.Q^T): consumes kf ----
        f32x4 svA[4], svB[4];
        #pragma unroll
        for (int s = 0; s < 4; ++s) {
            f32x4 a = {0.f, 0.f, 0.f, 0.f};
            a = MFMA16(kf[s][0], qfB[0], a);
            a = MFMA16(kf[s][1], qfB[1], a);
            svB[s] = a;
            if (actA) {
                f32x4 b = {0.f, 0.f, 0.f, 0.f};
                b = MFMA16(kf[s][0], qfA[0], b);
                b = MFMA16(kf[s][1], qfA[1], b);
                svA[s] = b;
            }
        }

        // ---- prefetch next step's K (off critical path) ----
        if (kc < diagB) {
            const short* kb = Kxbh + (kc + 1) * 4096;
            #pragma unroll
            for (int s = 0; s < 4; ++s) {
                kf[s][0] = *(const bf16x8*)&kb[(s * 2 + 0) * 512 + lofs];
                kf[s][1] = *(const bf16x8*)&kb[(s * 2 + 1) * 512 + lofs];
            }
        }

        // ---- softmax + P^T -> per-wave LDS (8B packed writes) ----
        if (kc == diagB) {
            const int qq = q0B + l16;
            #pragma unroll
            for (int s = 0; s < 4; ++s) {
                const int keyb = key0 + s * 16 + quad * 4;
                #pragma unroll
                for (int r = 0; r < 4; ++r)
                    svB[s][r] = (keyb + r <= qq) ? svB[s][r] : -1e30f;
            }
        }
        #pragma unroll
        for (int s = 0; s < 4; ++s) {
            #pragma unroll
            for (int r = 0; r < 4; ++r) svB[s][r] = exp2f(svB[s][r]);
            laccB += (svB[s][0] + svB[s][1]) + (svB[s][2] + svB[s][3]);
            uint2 pk = {pk_bf16(svB[s][0], svB[s][1]), pk_bf16(svB[s][2], svB[s][3])};
            *(uint2*)&pwB[l16 * 72 + s * 16 + quad * 4] = pk;
        }
        if (actA) {
            if (kc == diagA) {
                const int qq = q0A + l16;
                #pragma unroll
                for (int s = 0; s < 4; ++s) {
                    const int keyb = key0 + s * 16 + quad * 4;
                    #pragma unroll
                    for (int r = 0; r < 4; ++r)
                        svA[s][r] = (keyb + r <= qq) ? svA[s][r] : -1e30f;
                }
            }
            #pragma unroll
            for (int s = 0; s < 4; ++s) {
                #pragma unroll
                for (int r = 0; r < 4; ++r) svA[s][r] = exp2f(svA[s][r]);
                laccA += (svA[s][0] + svA[s][1]) + (svA[s][2] + svA[s][3]);
                uint2 pk = {pk_bf16(svA[s][0], svA[s][1]), pk_bf16(svA[s][2], svA[s][3])};
                *(uint2*)&pwA[l16 * 72 + s * 16 + quad * 4] = pk;
            }
        }

        // ---- PV (O^T += V^T.P^T); wave-internal DS is in-order ----
        {
            bf16x8 pfB0 = *(const bf16x8*)&pwB[l16 * 72 + quad * 8];
            bf16x8 pfB1 = *(const bf16x8*)&pwB[l16 * 72 + 32 + quad * 8];
            #pragma unroll
            for (int dt = 0; dt < 4; ++dt) {
                otB[dt] = MFMA16(vf[0][dt], pfB0, otB[dt]);
                otB[dt] = MFMA16(vf[1][dt], pfB1, otB[dt]);
            }
            if (actA) {
                bf16x8 pfA0 = *(const bf16x8*)&pwA[l16 * 72 + quad * 8];
                bf16x8 pfA1 = *(const bf16x8*)&pwA[l16 * 72 + 32 + quad * 8];
                #pragma unroll
                for (int dt = 0; dt < 4; ++dt) {
                    otA[dt] = MFMA16(vf[0][dt], pfA0, otA[dt]);
                    otA[dt] = MFMA16(vf[1][dt], pfA1, otA[dt]);
                }
            }
        }
    }

    // ---- l reduction (lanes sharing l16 across quads) + epilogue ----
    laccA += __shfl_xor(laccA, 16);
    laccA += __shfl_xor(laccA, 32);
    laccB += __shfl_xor(laccB, 16);
    laccB += __shfl_xor(laccB, 32);
    const float invA = 1.0f / laccA, invB = 1.0f / laccB;

    #pragma unroll
    for (int dt = 0; dt < 4; ++dt) {
        uint2 pa = {pk_bf16(otA[dt][0] * invA, otA[dt][1] * invA),
                    pk_bf16(otA[dt][2] * invA, otA[dt][3] * invA)};
        *(uint2*)&pwA[l16 * 72 + dt * 16 + quad * 4] = pa;
        uint2 pb = {pk_bf16(otB[dt][0] * invB, otB[dt][1] * invB),
                    pk_bf16(otB[dt][2] * invB, otB[dt][3] * invB)};
        *(uint2*)&pwB[l16 * 72 + dt * 16 + quad * 4] = pb;
    }
    {
        const int qr = lane >> 2, dc = (lane & 3) * 16;
        bf16x8 a0 = *(const bf16x8*)&pwA[qr * 72 + dc];
        bf16x8 a1 = *(const bf16x8*)&pwA[qr * 72 + dc + 8];
        short* dstA = &comb[(rowbase + q0A + qr) * 1024 + hcol + dc];
        *(bf16x8*)dstA = a0;
        *(bf16x8*)(dstA + 8) = a1;
        bf16x8 b0 = *(const bf16x8*)&pwB[qr * 72 + dc];
        bf16x8 b1 = *(const bf16x8*)&pwB[qr * 72 + dc + 8];
        short* dstB = &comb[(rowbase + q0B + qr) * 1024 + hcol + dc];
        *(bf16x8*)dstB = b0;
        *(bf16x8*)(dstB + 8) = b1;
    }
}

// ---------- launch ----------
extern "C" void kernel_launch(void* const* d_in, const int* in_sizes, int n_in,
                              void* d_out, int out_size, void* d_ws, size_t ws_size,
                              hipStream_t stream)
{
    const float* enc = (const float*)d_in[0];
    const float* Wa  = (const float*)d_in[1];
    const float* ba  = (const float*)d_in[2];
    const float* Wo  = (const float*)d_in[3];
    const float* bo  = (const float*)d_in[4];
    float* out = (float*)d_out;

    // layout (41 MB peak):
    // [0,8)  Abf (dead after gemm1) -> comb
    // [8,10) WtO  [10,11) biases  [11,17) WtA
    // [17,25) Kx  [25,33) Vx  [33,41) Qw
    char* ws = (char*)d_ws;
    short* Abf  = (short*)ws;
    short* comb = (short*)ws;
    short* WtO  = (short*)(ws + ((size_t)8 << 20));
    short* bbA  = (short*)(ws + ((size_t)10 << 20));
    short* bbO  = (short*)(ws + ((size_t)10 << 20) + 16384);
    short* WtA  = (short*)(ws + ((size_t)11 << 20));
    short* Kx   = (short*)(ws + ((size_t)17 << 20));
    short* Vx   = (short*)(ws + ((size_t)25 << 20));
    short* Qw   = (short*)(ws + ((size_t)33 << 20));

    prep_kernel<<<3074, 256, 0, stream>>>(enc, Wa, ba, Wo, bo, Abf, WtA, bbA, WtO, bbO);
    gemm_bt<128, false, true><<<dim3(24, 32), 256, 0, stream>>>(
        Abf, WtA, bbA, Qw, Kx, Vx, 4096, 3072, 1024);
    attn_kernel<<<dim3(32, 32), 128, 0, stream>>>(Qw, Kx, Vx, comb);
    gemm_bt<64, true, false><<<dim3(16, 32), 256, 0, stream>>>(
        comb, WtO, bbO, out, nullptr, nullptr, 4096, 1024, 1024);
}